// Round 5
// baseline (684.894 us; speedup 1.0000x reference)
//
#include <hip/hip_runtime.h>

// AttentionCTS: qkv proj -> depthwise 3x3 conv -> temporal mix -> L2-norm
// q,k -> softmax(q k^T * temp) v -> out proj.   All f32 (no fp32 MFMA on CDNA4).

#define BB   4
#define DIM  64
#define HEADS 4
#define TT   10
#define HH   64
#define WW2  64
#define HW   4096          // HH*WW2
#define CPH  16            // DIM/HEADS
#define NQ   160           // CPH*TT
#define C3   192           // 3*DIM

// ---------------- Kernel 1/6: pointwise projection -------------------------------
// out[b,o,t,hw] = sum_c in[b,c,t,hw] * w[o*DIM+c].  COUT split over blockIdx.y;
// 2 outputs x 4 partial sums = 8 independent FMA chains (ILP).
template<int CHUNK>
__global__ __launch_bounds__(256) void k_proj(const float* __restrict__ x,
                                              const float* __restrict__ w,
                                              float* __restrict__ out,
                                              int cout_total) {
    int p   = blockIdx.x * 256 + threadIdx.x;        // position over (b,t,hw)
    int b   = p / (TT * HW);
    int rem = p - b * (TT * HW);
    int t   = rem >> 12;
    int hw  = rem & 4095;
    int o0  = blockIdx.y * CHUNK;
    const float* xp = x + ((size_t)(b * DIM) * TT + t) * HW + hw;
    float xr[DIM];
#pragma unroll
    for (int c = 0; c < DIM; ++c) xr[c] = xp[(size_t)c * TT * HW];
    float* op = out + ((size_t)b * cout_total * TT + t) * HW + hw;
    for (int oo = 0; oo < CHUNK; oo += 2) {
        const float* w0 = w + (o0 + oo) * DIM;       // uniform -> s_load
        const float* w1 = w0 + DIM;
        float a0 = 0.f, a1 = 0.f, a2 = 0.f, a3 = 0.f;
        float b0 = 0.f, b1 = 0.f, b2 = 0.f, b3 = 0.f;
#pragma unroll
        for (int c = 0; c < DIM; c += 4) {
            a0 += xr[c]     * w0[c];
            a1 += xr[c + 1] * w0[c + 1];
            a2 += xr[c + 2] * w0[c + 2];
            a3 += xr[c + 3] * w0[c + 3];
            b0 += xr[c]     * w1[c];
            b1 += xr[c + 1] * w1[c + 1];
            b2 += xr[c + 2] * w1[c + 2];
            b3 += xr[c + 3] * w1[c + 3];
        }
        op[(size_t)(o0 + oo)     * TT * HW] = (a0 + a1) + (a2 + a3);
        op[(size_t)(o0 + oo + 1) * TT * HW] = (b0 + b1) + (b2 + b3);
    }
}

// ---------------- Kernel 2: depthwise 3x3 conv + temporal mix + q/k sumsq -------
// 4 rows per wave: per t load 6 contiguous rows (halves loads vs 1-row/wave),
// 12 shuffles + 36 FMA per t (4x ILP). No LDS, no barriers.
__global__ __launch_bounds__(256) void k_conv_temporal(const float* __restrict__ A,
                                                       const float* __restrict__ wdw,
                                                       const float* __restrict__ wt,
                                                       const float* __restrict__ bt,
                                                       float* __restrict__ Bq,
                                                       float* __restrict__ nbuf) {
    int tid  = threadIdx.x;
    int lane = tid & 63;
    int wv   = tid >> 6;
    int blk  = blockIdx.x;                 // (b*C3 + c)*4 + quarter
    int qt   = blk & 3;
    int c    = (blk >> 2) % C3;
    int b    = blk / (4 * C3);
    int h0   = qt * 16 + wv * 4;           // first of this wave's 4 rows

    float wd[9];
#pragma unroll
    for (int k = 0; k < 9; ++k) wd[k] = wdw[c * 9 + k];    // uniform -> sgpr

    const float* Ab = A + (size_t)(b * C3 + c) * TT * HW + h0 * WW2 + lane;
    bool hasU = (h0 > 0), hasD = (h0 + 4 < HH);

    float cv[4][TT];
#pragma unroll
    for (int t = 0; t < TT; ++t) {
        const float* p = Ab + (size_t)t * HW;
        // 6 rows h0-1 .. h0+4
        float r[6];
        r[0] = hasU ? p[-WW2] : 0.f;
        r[1] = p[0];
        r[2] = p[WW2];
        r[3] = p[2 * WW2];
        r[4] = p[3 * WW2];
        r[5] = hasD ? p[4 * WW2] : 0.f;
        float lf[6], rt[6];
#pragma unroll
        for (int i = 0; i < 6; ++i) {
            lf[i] = __shfl_up(r[i], 1);   if (lane == 0)  lf[i] = 0.f;
            rt[i] = __shfl_down(r[i], 1); if (lane == 63) rt[i] = 0.f;
        }
#pragma unroll
        for (int i = 0; i < 4; ++i) {
            cv[i][t] = lf[i]     * wd[0] + r[i]     * wd[1] + rt[i]     * wd[2]
                     + lf[i + 1] * wd[3] + r[i + 1] * wd[4] + rt[i + 1] * wd[5]
                     + lf[i + 2] * wd[6] + r[i + 2] * wd[7] + rt[i + 2] * wd[8];
        }
    }

    // temporal mix + store + sumsq, one output row at a time (caps VGPR peak)
    size_t obase = (size_t)(b * C3 + c) * TT * HW + h0 * WW2 + lane;
    bool doSS = (c < 128);
#pragma unroll
    for (int i = 0; i < 4; ++i) {
        float ov[TT];
#pragma unroll
        for (int s = 0; s < TT; ++s) {
            float v = bt[s];
#pragma unroll
            for (int t = 0; t < TT; ++t) v += cv[i][t] * wt[s * TT + t];
            ov[s] = v;
        }
#pragma unroll
        for (int s = 0; s < TT; ++s)
            Bq[obase + (size_t)i * WW2 + (size_t)s * HW] = ov[s];
        if (doSS) {
            float ss[TT];
#pragma unroll
            for (int s = 0; s < TT; ++s) ss[s] = ov[s] * ov[s];
#pragma unroll
            for (int off = 32; off > 0; off >>= 1) {
#pragma unroll
                for (int s = 0; s < TT; ++s) ss[s] += __shfl_xor(ss[s], off);
            }
            if (lane == 0) {
#pragma unroll
                for (int s = 0; s < TT; ++s)
                    atomicAdd(&nbuf[(size_t)(b * 128 + c) * TT + s], ss[s]);
            }
        }
    }
}

// ---------------- Kernel 3: partial scores S_part[split] = q k^T over d-chunk ----
// grid = (16 bh * 25 tiles, 4 splits); 32x32 S-tile; 2x2 outputs/thread.
// Normalization/temperature applied later in k_softmax.
__global__ __launch_bounds__(256) void k_scores(const float* __restrict__ Bq,
                                                float* __restrict__ Spart) {
    __shared__ float ldsQ[32 * 68];
    __shared__ float ldsK[32 * 68];
    int blk = blockIdx.x;
    int bh  = blk / 25;
    int rr  = blk - bh * 25;
    int nt  = rr / 5, mt = rr - nt * 5;
    int b   = bh >> 2, h = bh & 3;
    int split = blockIdx.y;
    const float* Qb = Bq + ((size_t)(b * C3 + h * CPH) * TT) * HW + (size_t)nt * 32 * HW;
    const float* Kb = Bq + ((size_t)(b * C3 + 64 + h * CPH) * TT) * HW + (size_t)mt * 32 * HW;
    int tid = threadIdx.x;
    int r   = tid >> 3, cg = (tid & 7) * 8;
    int np  = (tid >> 4) * 2, mp = (tid & 15) * 2;
    float a00 = 0, a01 = 0, a10 = 0, a11 = 0;
    int dlo = split * (HW / 4), dhi = dlo + (HW / 4);
    for (int d0 = dlo; d0 < dhi; d0 += 64) {
        __syncthreads();
        float4 q0 = *(const float4*)(Qb + (size_t)r * HW + d0 + cg);
        float4 q1 = *(const float4*)(Qb + (size_t)r * HW + d0 + cg + 4);
        float4 k0 = *(const float4*)(Kb + (size_t)r * HW + d0 + cg);
        float4 k1 = *(const float4*)(Kb + (size_t)r * HW + d0 + cg + 4);
        *(float4*)(ldsQ + r * 68 + cg)     = q0;
        *(float4*)(ldsQ + r * 68 + cg + 4) = q1;
        *(float4*)(ldsK + r * 68 + cg)     = k0;
        *(float4*)(ldsK + r * 68 + cg + 4) = k1;
        __syncthreads();
#pragma unroll
        for (int dd = 0; dd < 64; dd += 4) {
            float4 qa = *(const float4*)(ldsQ + np * 68 + dd);
            float4 qb = *(const float4*)(ldsQ + (np + 1) * 68 + dd);
            float4 ka = *(const float4*)(ldsK + mp * 68 + dd);
            float4 kb = *(const float4*)(ldsK + (mp + 1) * 68 + dd);
            a00 += qa.x * ka.x + qa.y * ka.y + qa.z * ka.z + qa.w * ka.w;
            a01 += qa.x * kb.x + qa.y * kb.y + qa.z * kb.z + qa.w * kb.w;
            a10 += qb.x * ka.x + qb.y * ka.y + qb.z * ka.z + qb.w * ka.w;
            a11 += qb.x * kb.x + qb.y * kb.y + qb.z * kb.z + qb.w * kb.w;
        }
    }
    int n = nt * 32 + np, m = mt * 32 + mp;
    size_t sb = (size_t)split * (16 * NQ * NQ) + ((size_t)bh * NQ + n) * NQ + m;
    Spart[sb]          = a00;
    Spart[sb + 1]      = a01;
    Spart[sb + NQ]     = a10;
    Spart[sb + NQ + 1] = a11;
}

// ---------------- Kernel 4: sum partials, scale, softmax over m, write P^T -------
__global__ __launch_bounds__(256) void k_softmax(const float* __restrict__ Spart,
                                                 const float* __restrict__ nbuf,
                                                 const float* __restrict__ temp,
                                                 float* __restrict__ PT) {
    const int SS = 16 * NQ * NQ;
    int r    = blockIdx.x * 4 + (threadIdx.x >> 6);   // row id 0..2559 (= bh*160+n)
    int lane = threadIdx.x & 63;
    const float* Sr = Spart + (size_t)r * NQ;
    float v0 = 0.f, v1 = 0.f, v2 = 0.f;
#pragma unroll
    for (int sp = 0; sp < 4; ++sp) {
        v0 += Sr[sp * SS + lane];
        v1 += Sr[sp * SS + lane + 64];
        if (lane < 32) v2 += Sr[sp * SS + lane + 128];
    }
    int bh = r / NQ, n = r - bh * NQ;
    int b  = bh >> 2, h = bh & 3;
    const float eps = 1e-12f;
    float tp  = temp[h];
    float iqn = tp / fmaxf(sqrtf(nbuf[b * 1280 + h * 160 + n]), eps);       // uniform
    float ik0 = 1.f / fmaxf(sqrtf(nbuf[b * 1280 + 640 + h * 160 + lane]), eps);
    float ik1 = 1.f / fmaxf(sqrtf(nbuf[b * 1280 + 640 + h * 160 + lane + 64]), eps);
    float ik2 = (lane < 32) ? 1.f / fmaxf(sqrtf(nbuf[b * 1280 + 640 + h * 160 + lane + 128]), eps) : 1.f;
    v0 *= iqn * ik0;
    v1 *= iqn * ik1;
    v2 = (lane < 32) ? v2 * iqn * ik2 : -1e30f;
    float mx = fmaxf(fmaxf(v0, v1), v2);
#pragma unroll
    for (int off = 32; off > 0; off >>= 1) mx = fmaxf(mx, __shfl_xor(mx, off));
    float e0 = expf(v0 - mx), e1 = expf(v1 - mx);
    float e2 = (lane < 32) ? expf(v2 - mx) : 0.f;
    float sm = e0 + e1 + e2;
#pragma unroll
    for (int off = 32; off > 0; off >>= 1) sm += __shfl_xor(sm, off);
    float inv = 1.f / sm;
    float* Pb = PT + (size_t)bh * NQ * NQ + n;
    Pb[(size_t)lane * NQ]        = e0 * inv;
    Pb[(size_t)(lane + 64) * NQ] = e1 * inv;
    if (lane < 32) Pb[(size_t)(lane + 128) * NQ] = e2 * inv;
}

// ---------------- Kernel 5: O = P V ----------------------------------------------
// grid = bh(16) * dtile(16 x 256 cols) * nq(4 x 40 rows); P^T rows via scalar loads
__global__ __launch_bounds__(256) void k_pv(const float* __restrict__ Bq,
                                            const float* __restrict__ PT,
                                            float* __restrict__ O) {
    int blk  = blockIdx.x;
    int nq   = blk & 3;
    int dt   = (blk >> 2) & 15;
    int bh   = blk >> 6;
    int b    = bh >> 2, h = bh & 3;
    int d    = dt * 256 + threadIdx.x;
    int n0   = nq * 40;
    const float* Vb  = Bq + ((size_t)(b * C3 + 128 + h * CPH) * TT) * HW;
    const float* PTb = PT + (size_t)bh * NQ * NQ;
    float* Ob = O + ((size_t)(b * DIM + h * CPH) * TT) * HW;
    float acc[40];
#pragma unroll
    for (int j = 0; j < 40; ++j) acc[j] = 0.f;
    for (int m = 0; m < NQ; ++m) {
        float vv = Vb[(size_t)m * HW + d];
        const float* pr = PTb + m * NQ + n0;      // uniform -> s_load
#pragma unroll
        for (int j = 0; j < 40; ++j) acc[j] += pr[j] * vv;
    }
#pragma unroll
    for (int j = 0; j < 40; ++j) Ob[(size_t)(n0 + j) * HW + d] = acc[j];
}

extern "C" void kernel_launch(void* const* d_in, const int* in_sizes, int n_in,
                              void* d_out, int out_size, void* d_ws, size_t ws_size,
                              hipStream_t stream) {
    const float* x    = (const float*)d_in[0];
    const float* wqkv = (const float*)d_in[1];
    const float* wdw  = (const float*)d_in[2];
    const float* wt   = (const float*)d_in[3];
    const float* bt   = (const float*)d_in[4];
    const float* temp = (const float*)d_in[5];
    const float* wout = (const float*)d_in[6];
    float* out = (float*)d_out;

    const size_t SA = (size_t)BB * C3 * TT * HW;       // 31,457,280 floats
    const size_t SN = (size_t)BB * 128 * TT;           // 5,120
    const size_t SS = (size_t)16 * NQ * NQ;            // 409,600
    const size_t SO = (size_t)BB * DIM * TT * HW;      // 10,485,760

    float* bufA = (float*)d_ws;          // region0: qkv-proj out; later reused
    float* bufB = bufA + SA;             // conv+temporal out (q|k|v)
    float* nbuf = bufB + SA;             // q/k row sumsq
    // reuse region0 after k_conv_temporal consumed bufA:
    float* Obuf  = bufA;                 // attn output (SO floats)
    float* Spart = bufA + SO;            // partial scores (4*SS floats)
    float* PTbf  = Spart + 4 * SS;       // P^T (SS floats)

    if (ws_size < (2 * SA + SN) * sizeof(float)) return;  // scratch too small

    (void)hipMemsetAsync(nbuf, 0, SN * sizeof(float), stream);

    k_proj<64><<<dim3(640, 3), dim3(256), 0, stream>>>(x, wqkv, bufA, C3);
    k_conv_temporal<<<dim3(3072), dim3(256), 0, stream>>>(bufA, wdw, wt, bt, bufB, nbuf);
    k_scores<<<dim3(400, 4), dim3(256), 0, stream>>>(bufB, Spart);
    k_softmax<<<dim3(640), dim3(256), 0, stream>>>(Spart, nbuf, temp, PTbf);
    k_pv<<<dim3(1024), dim3(256), 0, stream>>>(bufB, PTbf, Obuf);
    k_proj<32><<<dim3(640, 2), dim3(256), 0, stream>>>(Obuf, wout, out, DIM);
}

// Round 6
// 483.069 us; speedup vs baseline: 1.4178x; 1.4178x over previous
//
#include <hip/hip_runtime.h>

// AttentionCTS: qkv proj -> depthwise 3x3 conv -> temporal mix -> L2-norm
// q,k -> softmax(q k^T * temp) v -> out proj.   All f32 (no fp32 MFMA on CDNA4).

#define BB   4
#define DIM  64
#define HEADS 4
#define TT   10
#define HH   64
#define WW2  64
#define HW   4096          // HH*WW2
#define CPH  16            // DIM/HEADS
#define NQ   160           // CPH*TT
#define C3   192           // 3*DIM

// ---------------- Kernel 0: weight transpose (tiny) ------------------------------
__global__ __launch_bounds__(256) void k_transpose(const float* __restrict__ w,
                                                   float* __restrict__ wT,
                                                   int O, int C) {
    int idx = blockIdx.x * 256 + threadIdx.x;
    if (idx < O * C) {
        int o = idx / C, c = idx - o * C;
        wT[c * O + o] = w[idx];
    }
}

// ---------------- Kernel 1/6: pointwise projection (register-blocked GEMM) -------
// out[b,o,t,hw] = sum_c x[b,c,t,hw] * w[o,c].  Thread owns 4 consecutive hw
// (float4 = 1KB/wave granule); CHUNK outputs per block (acc float4[CHUNK]);
// weights pre-transposed so per-c chunk is contiguous (s_load_dwordx4).
template<int CHUNK>
__global__ __launch_bounds__(256) void k_proj(const float* __restrict__ x,
                                              const float* __restrict__ wT,  // [DIM][cout_total]
                                              float* __restrict__ out,
                                              int cout_total) {
    int P   = blockIdx.x * 1024 + threadIdx.x * 4;   // position over (b,t,hw)
    int b   = P / (TT * HW);
    int rem = P - b * (TT * HW);
    int t   = rem >> 12;
    int hw  = rem & 4095;
    int o0  = blockIdx.y * CHUNK;
    const float* xp = x + ((size_t)(b * DIM) * TT + t) * HW + hw;
    float4 acc[CHUNK];
#pragma unroll
    for (int o = 0; o < CHUNK; ++o) acc[o] = make_float4(0.f, 0.f, 0.f, 0.f);
    for (int c = 0; c < DIM; ++c) {
        float4 xv = *(const float4*)(xp + (size_t)c * TT * HW);
        const float* wr = wT + c * cout_total + o0;      // uniform -> s_load x4
#pragma unroll
        for (int o = 0; o < CHUNK; ++o) {
            float wv = wr[o];
            acc[o].x += wv * xv.x;
            acc[o].y += wv * xv.y;
            acc[o].z += wv * xv.z;
            acc[o].w += wv * xv.w;
        }
    }
    float* op = out + ((size_t)b * cout_total * TT + t) * HW + hw;
#pragma unroll
    for (int o = 0; o < CHUNK; ++o)
        *(float4*)(op + (size_t)(o0 + o) * TT * HW) = acc[o];
}

// ---------------- Kernel 2: depthwise 3x3 conv + temporal mix + q/k sumsq -------
// 4 rows per wave: per t load 6 contiguous rows, 12 shuffles + 36 FMA per t.
__global__ __launch_bounds__(256) void k_conv_temporal(const float* __restrict__ A,
                                                       const float* __restrict__ wdw,
                                                       const float* __restrict__ wt,
                                                       const float* __restrict__ bt,
                                                       float* __restrict__ Bq,
                                                       float* __restrict__ nbuf) {
    int tid  = threadIdx.x;
    int lane = tid & 63;
    int wv   = tid >> 6;
    int blk  = blockIdx.x;                 // (b*C3 + c)*4 + quarter
    int qt   = blk & 3;
    int c    = (blk >> 2) % C3;
    int b    = blk / (4 * C3);
    int h0   = qt * 16 + wv * 4;           // first of this wave's 4 rows

    float wd[9];
#pragma unroll
    for (int k = 0; k < 9; ++k) wd[k] = wdw[c * 9 + k];    // uniform -> sgpr

    const float* Ab = A + (size_t)(b * C3 + c) * TT * HW + h0 * WW2 + lane;
    bool hasU = (h0 > 0), hasD = (h0 + 4 < HH);

    float cv[4][TT];
#pragma unroll
    for (int t = 0; t < TT; ++t) {
        const float* p = Ab + (size_t)t * HW;
        float r[6];
        r[0] = hasU ? p[-WW2] : 0.f;
        r[1] = p[0];
        r[2] = p[WW2];
        r[3] = p[2 * WW2];
        r[4] = p[3 * WW2];
        r[5] = hasD ? p[4 * WW2] : 0.f;
        float lf[6], rt[6];
#pragma unroll
        for (int i = 0; i < 6; ++i) {
            lf[i] = __shfl_up(r[i], 1);   if (lane == 0)  lf[i] = 0.f;
            rt[i] = __shfl_down(r[i], 1); if (lane == 63) rt[i] = 0.f;
        }
#pragma unroll
        for (int i = 0; i < 4; ++i) {
            cv[i][t] = lf[i]     * wd[0] + r[i]     * wd[1] + rt[i]     * wd[2]
                     + lf[i + 1] * wd[3] + r[i + 1] * wd[4] + rt[i + 1] * wd[5]
                     + lf[i + 2] * wd[6] + r[i + 2] * wd[7] + rt[i + 2] * wd[8];
        }
    }

    size_t obase = (size_t)(b * C3 + c) * TT * HW + h0 * WW2 + lane;
    bool doSS = (c < 128);
#pragma unroll
    for (int i = 0; i < 4; ++i) {
        float ov[TT];
#pragma unroll
        for (int s = 0; s < TT; ++s) {
            float v = bt[s];
#pragma unroll
            for (int t = 0; t < TT; ++t) v += cv[i][t] * wt[s * TT + t];
            ov[s] = v;
        }
#pragma unroll
        for (int s = 0; s < TT; ++s)
            Bq[obase + (size_t)i * WW2 + (size_t)s * HW] = ov[s];
        if (doSS) {
            float ss[TT];
#pragma unroll
            for (int s = 0; s < TT; ++s) ss[s] = ov[s] * ov[s];
#pragma unroll
            for (int off = 32; off > 0; off >>= 1) {
#pragma unroll
                for (int s = 0; s < TT; ++s) ss[s] += __shfl_xor(ss[s], off);
            }
            if (lane == 0) {
#pragma unroll
                for (int s = 0; s < TT; ++s)
                    atomicAdd(&nbuf[(size_t)(b * 128 + c) * TT + s], ss[s]);
            }
        }
    }
}

// ---------------- Kernel 3: partial scores S_part[split] = q k^T over d-chunk ----
__global__ __launch_bounds__(256) void k_scores(const float* __restrict__ Bq,
                                                float* __restrict__ Spart) {
    __shared__ float ldsQ[32 * 68];
    __shared__ float ldsK[32 * 68];
    int blk = blockIdx.x;
    int bh  = blk / 25;
    int rr  = blk - bh * 25;
    int nt  = rr / 5, mt = rr - nt * 5;
    int b   = bh >> 2, h = bh & 3;
    int split = blockIdx.y;
    const float* Qb = Bq + ((size_t)(b * C3 + h * CPH) * TT) * HW + (size_t)nt * 32 * HW;
    const float* Kb = Bq + ((size_t)(b * C3 + 64 + h * CPH) * TT) * HW + (size_t)mt * 32 * HW;
    int tid = threadIdx.x;
    int r   = tid >> 3, cg = (tid & 7) * 8;
    int np  = (tid >> 4) * 2, mp = (tid & 15) * 2;
    float a00 = 0, a01 = 0, a10 = 0, a11 = 0;
    int dlo = split * (HW / 4), dhi = dlo + (HW / 4);
    for (int d0 = dlo; d0 < dhi; d0 += 64) {
        __syncthreads();
        float4 q0 = *(const float4*)(Qb + (size_t)r * HW + d0 + cg);
        float4 q1 = *(const float4*)(Qb + (size_t)r * HW + d0 + cg + 4);
        float4 k0 = *(const float4*)(Kb + (size_t)r * HW + d0 + cg);
        float4 k1 = *(const float4*)(Kb + (size_t)r * HW + d0 + cg + 4);
        *(float4*)(ldsQ + r * 68 + cg)     = q0;
        *(float4*)(ldsQ + r * 68 + cg + 4) = q1;
        *(float4*)(ldsK + r * 68 + cg)     = k0;
        *(float4*)(ldsK + r * 68 + cg + 4) = k1;
        __syncthreads();
#pragma unroll
        for (int dd = 0; dd < 64; dd += 4) {
            float4 qa = *(const float4*)(ldsQ + np * 68 + dd);
            float4 qb = *(const float4*)(ldsQ + (np + 1) * 68 + dd);
            float4 ka = *(const float4*)(ldsK + mp * 68 + dd);
            float4 kb = *(const float4*)(ldsK + (mp + 1) * 68 + dd);
            a00 += qa.x * ka.x + qa.y * ka.y + qa.z * ka.z + qa.w * ka.w;
            a01 += qa.x * kb.x + qa.y * kb.y + qa.z * kb.z + qa.w * kb.w;
            a10 += qb.x * ka.x + qb.y * ka.y + qb.z * ka.z + qb.w * ka.w;
            a11 += qb.x * kb.x + qb.y * kb.y + qb.z * kb.z + qb.w * kb.w;
        }
    }
    int n = nt * 32 + np, m = mt * 32 + mp;
    size_t sb = (size_t)split * (16 * NQ * NQ) + ((size_t)bh * NQ + n) * NQ + m;
    Spart[sb]          = a00;
    Spart[sb + 1]      = a01;
    Spart[sb + NQ]     = a10;
    Spart[sb + NQ + 1] = a11;
}

// ---------------- Kernel 4: sum partials, scale, softmax over m, write P^T -------
__global__ __launch_bounds__(256) void k_softmax(const float* __restrict__ Spart,
                                                 const float* __restrict__ nbuf,
                                                 const float* __restrict__ temp,
                                                 float* __restrict__ PT) {
    const int SS = 16 * NQ * NQ;
    int r    = blockIdx.x * 4 + (threadIdx.x >> 6);   // row id 0..2559 (= bh*160+n)
    int lane = threadIdx.x & 63;
    const float* Sr = Spart + (size_t)r * NQ;
    float v0 = 0.f, v1 = 0.f, v2 = 0.f;
#pragma unroll
    for (int sp = 0; sp < 4; ++sp) {
        v0 += Sr[sp * SS + lane];
        v1 += Sr[sp * SS + lane + 64];
        if (lane < 32) v2 += Sr[sp * SS + lane + 128];
    }
    int bh = r / NQ, n = r - bh * NQ;
    int b  = bh >> 2, h = bh & 3;
    const float eps = 1e-12f;
    float tp  = temp[h];
    float iqn = tp / fmaxf(sqrtf(nbuf[b * 1280 + h * 160 + n]), eps);       // uniform
    float ik0 = 1.f / fmaxf(sqrtf(nbuf[b * 1280 + 640 + h * 160 + lane]), eps);
    float ik1 = 1.f / fmaxf(sqrtf(nbuf[b * 1280 + 640 + h * 160 + lane + 64]), eps);
    float ik2 = (lane < 32) ? 1.f / fmaxf(sqrtf(nbuf[b * 1280 + 640 + h * 160 + lane + 128]), eps) : 1.f;
    v0 *= iqn * ik0;
    v1 *= iqn * ik1;
    v2 = (lane < 32) ? v2 * iqn * ik2 : -1e30f;
    float mx = fmaxf(fmaxf(v0, v1), v2);
#pragma unroll
    for (int off = 32; off > 0; off >>= 1) mx = fmaxf(mx, __shfl_xor(mx, off));
    float e0 = expf(v0 - mx), e1 = expf(v1 - mx);
    float e2 = (lane < 32) ? expf(v2 - mx) : 0.f;
    float sm = e0 + e1 + e2;
#pragma unroll
    for (int off = 32; off > 0; off >>= 1) sm += __shfl_xor(sm, off);
    float inv = 1.f / sm;
    float* Pb = PT + (size_t)bh * NQ * NQ + n;
    Pb[(size_t)lane * NQ]        = e0 * inv;
    Pb[(size_t)(lane + 64) * NQ] = e1 * inv;
    if (lane < 32) Pb[(size_t)(lane + 128) * NQ] = e2 * inv;
}

// ---------------- Kernel 5: O = P V ----------------------------------------------
// grid = bh(16) x dt(8 x 512d) x nq(8 x 20 rows); thread = 2 consecutive d (float2)
__global__ __launch_bounds__(256) void k_pv(const float* __restrict__ Bq,
                                            const float* __restrict__ PT,
                                            float* __restrict__ O) {
    int blk  = blockIdx.x;
    int nq   = blk & 7;
    int dt   = (blk >> 3) & 7;
    int bh   = blk >> 6;
    int b    = bh >> 2, h = bh & 3;
    int d    = dt * 512 + threadIdx.x * 2;
    int n0   = nq * 20;
    const float* Vb  = Bq + ((size_t)(b * C3 + 128 + h * CPH) * TT) * HW;
    const float* PTb = PT + (size_t)bh * NQ * NQ;
    float* Ob = O + ((size_t)(b * DIM + h * CPH) * TT) * HW;
    float2 acc[20];
#pragma unroll
    for (int j = 0; j < 20; ++j) acc[j] = make_float2(0.f, 0.f);
    for (int m = 0; m < NQ; ++m) {
        float2 vv = *(const float2*)(Vb + (size_t)m * HW + d);
        const float* pr = PTb + m * NQ + n0;      // uniform -> s_load
#pragma unroll
        for (int j = 0; j < 20; ++j) {
            acc[j].x += pr[j] * vv.x;
            acc[j].y += pr[j] * vv.y;
        }
    }
#pragma unroll
    for (int j = 0; j < 20; ++j)
        *(float2*)(Ob + (size_t)(n0 + j) * HW + d) = acc[j];
}

extern "C" void kernel_launch(void* const* d_in, const int* in_sizes, int n_in,
                              void* d_out, int out_size, void* d_ws, size_t ws_size,
                              hipStream_t stream) {
    const float* x    = (const float*)d_in[0];
    const float* wqkv = (const float*)d_in[1];
    const float* wdw  = (const float*)d_in[2];
    const float* wt   = (const float*)d_in[3];
    const float* bt   = (const float*)d_in[4];
    const float* temp = (const float*)d_in[5];
    const float* wout = (const float*)d_in[6];
    float* out = (float*)d_out;

    const size_t SA = (size_t)BB * C3 * TT * HW;       // 31,457,280 floats
    const size_t SN = (size_t)BB * 128 * TT;           // 5,120
    const size_t SS = (size_t)16 * NQ * NQ;            // 409,600
    const size_t SO = (size_t)BB * DIM * TT * HW;      // 10,485,760

    float* bufA = (float*)d_ws;          // region0: qkv-proj out; later reused
    float* bufB = bufA + SA;             // conv+temporal out (q|k|v)
    float* nbuf = bufB + SA;             // q/k row sumsq
    float* wT1  = nbuf + SN;             // transposed w_qkv [64][192]
    float* wT2  = wT1 + 64 * C3;         // transposed w_out [64][64]
    // reuse region0 after k_conv_temporal consumed bufA:
    float* Obuf  = bufA;                 // attn output (SO floats)
    float* Spart = bufA + SO;            // partial scores (4*SS floats)
    float* PTbf  = Spart + 4 * SS;       // P^T (SS floats)

    if (ws_size < (2 * SA + SN + 64 * C3 + 64 * DIM) * sizeof(float)) return;

    (void)hipMemsetAsync(nbuf, 0, SN * sizeof(float), stream);

    k_transpose<<<dim3(48), dim3(256), 0, stream>>>(wqkv, wT1, C3, DIM);
    k_transpose<<<dim3(16), dim3(256), 0, stream>>>(wout, wT2, DIM, DIM);

    k_proj<16><<<dim3(160, 12), dim3(256), 0, stream>>>(x, wT1, bufA, C3);
    k_conv_temporal<<<dim3(3072), dim3(256), 0, stream>>>(bufA, wdw, wt, bt, bufB, nbuf);
    k_scores<<<dim3(400, 4), dim3(256), 0, stream>>>(bufB, Spart);
    k_softmax<<<dim3(640), dim3(256), 0, stream>>>(Spart, nbuf, temp, PTbf);
    k_pv<<<dim3(1024), dim3(256), 0, stream>>>(bufB, PTbf, Obuf);
    k_proj<8><<<dim3(160, 8), dim3(256), 0, stream>>>(Obuf, wT2, out, DIM);
}

// Round 7
// 422.159 us; speedup vs baseline: 1.6224x; 1.1443x over previous
//
#include <hip/hip_runtime.h>

// AttentionCTS: qkv proj -> depthwise 3x3 conv -> temporal mix -> L2-norm
// q,k -> softmax(q k^T * temp) v -> out proj.   All f32 (no fp32 MFMA on CDNA4).

#define BB   4
#define DIM  64
#define HEADS 4
#define TT   10
#define HH   64
#define WW2  64
#define HW   4096          // HH*WW2
#define CPH  16            // DIM/HEADS
#define NQ   160           // CPH*TT
#define C3   192           // 3*DIM

// ---------------- Kernel 0: weight transpose (tiny) ------------------------------
__global__ __launch_bounds__(256) void k_transpose(const float* __restrict__ w,
                                                   float* __restrict__ wT,
                                                   int O, int C) {
    int idx = blockIdx.x * 256 + threadIdx.x;
    if (idx < O * C) {
        int o = idx / C, c = idx - o * C;
        wT[c * O + o] = w[idx];
    }
}

// ---------------- Kernel 1/6: pointwise projection (register-blocked GEMM) -------
template<int CHUNK>
__global__ __launch_bounds__(256) void k_proj(const float* __restrict__ x,
                                              const float* __restrict__ wT,  // [DIM][cout_total]
                                              float* __restrict__ out,
                                              int cout_total) {
    int P   = blockIdx.x * 1024 + threadIdx.x * 4;   // position over (b,t,hw)
    int b   = P / (TT * HW);
    int rem = P - b * (TT * HW);
    int t   = rem >> 12;
    int hw  = rem & 4095;
    int o0  = blockIdx.y * CHUNK;
    const float* xp = x + ((size_t)(b * DIM) * TT + t) * HW + hw;
    float4 acc[CHUNK];
#pragma unroll
    for (int o = 0; o < CHUNK; ++o) acc[o] = make_float4(0.f, 0.f, 0.f, 0.f);
    for (int c = 0; c < DIM; ++c) {
        float4 xv = *(const float4*)(xp + (size_t)c * TT * HW);
        const float* wr = wT + c * cout_total + o0;      // uniform -> s_load x4
#pragma unroll
        for (int o = 0; o < CHUNK; ++o) {
            float wv = wr[o];
            acc[o].x += wv * xv.x;
            acc[o].y += wv * xv.y;
            acc[o].z += wv * xv.z;
            acc[o].w += wv * xv.w;
        }
    }
    float* op = out + ((size_t)b * cout_total * TT + t) * HW + hw;
#pragma unroll
    for (int o = 0; o < CHUNK; ++o)
        *(float4*)(op + (size_t)(o0 + o) * TT * HW) = acc[o];
}

// ---------------- Kernel 2: depthwise 3x3 conv + temporal mix + q/k sumsq -------
// float4-per-lane: 16 lanes x 4w cover one row; 4 row-groups = wave's 4-row strip.
// Per t: 3 x 1KB row loads (u/m/d), 6 edge shuffles, 36 FMA. Sumsq: dot4 then
// one 6-level x 10s butterfly (60 shuffles, was 240). Stores: 10 x 1KB.
__global__ __launch_bounds__(256) void k_conv_temporal(const float* __restrict__ A,
                                                       const float* __restrict__ wdw,
                                                       const float* __restrict__ wt,
                                                       const float* __restrict__ bt,
                                                       float* __restrict__ Bq,
                                                       float* __restrict__ nbuf) {
    int tid  = threadIdx.x;
    int lane = tid & 63;
    int wv   = tid >> 6;
    int li   = lane & 15;                  // w-group: w = li*4
    int g    = lane >> 4;                  // row within wave's 4-row strip
    int blk  = blockIdx.x;                 // (b*C3 + c)*4 + quarter
    int qt   = blk & 3;
    int c    = (blk >> 2) % C3;
    int b    = blk / (4 * C3);
    int row  = qt * 16 + wv * 4 + g;

    float wd[9];
#pragma unroll
    for (int k = 0; k < 9; ++k) wd[k] = wdw[c * 9 + k];    // uniform -> sgpr

    const float* Ab = A + (size_t)(b * C3 + c) * TT * HW + row * WW2 + li * 4;
    bool hasU = (row > 0), hasD = (row < HH - 1);
    const float4 z4 = make_float4(0.f, 0.f, 0.f, 0.f);

    float4 cv4[TT];
#pragma unroll
    for (int t = 0; t < TT; ++t) {
        const float* p = Ab + (size_t)t * HW;
        float4 u = hasU ? *(const float4*)(p - WW2) : z4;
        float4 m = *(const float4*)(p);
        float4 d = hasD ? *(const float4*)(p + WW2) : z4;
        float uL = __shfl_up(u.w, 1);   if (li == 0)  uL = 0.f;
        float mL = __shfl_up(m.w, 1);   if (li == 0)  mL = 0.f;
        float dL = __shfl_up(d.w, 1);   if (li == 0)  dL = 0.f;
        float uR = __shfl_down(u.x, 1); if (li == 15) uR = 0.f;
        float mR = __shfl_down(m.x, 1); if (li == 15) mR = 0.f;
        float dR = __shfl_down(d.x, 1); if (li == 15) dR = 0.f;
        float4 r;
        r.x = uL  * wd[0] + u.x * wd[1] + u.y * wd[2]
            + mL  * wd[3] + m.x * wd[4] + m.y * wd[5]
            + dL  * wd[6] + d.x * wd[7] + d.y * wd[8];
        r.y = u.x * wd[0] + u.y * wd[1] + u.z * wd[2]
            + m.x * wd[3] + m.y * wd[4] + m.z * wd[5]
            + d.x * wd[6] + d.y * wd[7] + d.z * wd[8];
        r.z = u.y * wd[0] + u.z * wd[1] + u.w * wd[2]
            + m.y * wd[3] + m.z * wd[4] + m.w * wd[5]
            + d.y * wd[6] + d.z * wd[7] + d.w * wd[8];
        r.w = u.z * wd[0] + u.w * wd[1] + uR  * wd[2]
            + m.z * wd[3] + m.w * wd[4] + mR  * wd[5]
            + d.z * wd[6] + d.w * wd[7] + dR  * wd[8];
        cv4[t] = r;
    }

    size_t obase = (size_t)(b * C3 + c) * TT * HW + row * WW2 + li * 4;
    bool doSS = (c < 128);
    float ss[TT];
#pragma unroll
    for (int s = 0; s < TT; ++s) {
        float bs = bt[s];
        float4 ov = make_float4(bs, bs, bs, bs);
#pragma unroll
        for (int t = 0; t < TT; ++t) {
            float wv_ = wt[s * TT + t];
            ov.x += cv4[t].x * wv_;
            ov.y += cv4[t].y * wv_;
            ov.z += cv4[t].z * wv_;
            ov.w += cv4[t].w * wv_;
        }
        *(float4*)(Bq + obase + (size_t)s * HW) = ov;
        ss[s] = ov.x * ov.x + ov.y * ov.y + ov.z * ov.z + ov.w * ov.w;
    }

    if (doSS) {
#pragma unroll
        for (int off = 32; off > 0; off >>= 1) {
#pragma unroll
            for (int s = 0; s < TT; ++s) ss[s] += __shfl_xor(ss[s], off);
        }
        if (lane == 0) {
#pragma unroll
            for (int s = 0; s < TT; ++s)
                atomicAdd(&nbuf[(size_t)(b * 128 + c) * TT + s], ss[s]);
        }
    }
}

// ---------------- Kernel 3: partial scores S_part[split] = q k^T over d-chunk ----
__global__ __launch_bounds__(256) void k_scores(const float* __restrict__ Bq,
                                                float* __restrict__ Spart) {
    __shared__ float ldsQ[32 * 68];
    __shared__ float ldsK[32 * 68];
    int blk = blockIdx.x;
    int bh  = blk / 25;
    int rr  = blk - bh * 25;
    int nt  = rr / 5, mt = rr - nt * 5;
    int b   = bh >> 2, h = bh & 3;
    int split = blockIdx.y;
    const float* Qb = Bq + ((size_t)(b * C3 + h * CPH) * TT) * HW + (size_t)nt * 32 * HW;
    const float* Kb = Bq + ((size_t)(b * C3 + 64 + h * CPH) * TT) * HW + (size_t)mt * 32 * HW;
    int tid = threadIdx.x;
    int r   = tid >> 3, cg = (tid & 7) * 8;
    int np  = (tid >> 4) * 2, mp = (tid & 15) * 2;
    float a00 = 0, a01 = 0, a10 = 0, a11 = 0;
    int dlo = split * (HW / 4), dhi = dlo + (HW / 4);
    for (int d0 = dlo; d0 < dhi; d0 += 64) {
        __syncthreads();
        float4 q0 = *(const float4*)(Qb + (size_t)r * HW + d0 + cg);
        float4 q1 = *(const float4*)(Qb + (size_t)r * HW + d0 + cg + 4);
        float4 k0 = *(const float4*)(Kb + (size_t)r * HW + d0 + cg);
        float4 k1 = *(const float4*)(Kb + (size_t)r * HW + d0 + cg + 4);
        *(float4*)(ldsQ + r * 68 + cg)     = q0;
        *(float4*)(ldsQ + r * 68 + cg + 4) = q1;
        *(float4*)(ldsK + r * 68 + cg)     = k0;
        *(float4*)(ldsK + r * 68 + cg + 4) = k1;
        __syncthreads();
#pragma unroll
        for (int dd = 0; dd < 64; dd += 4) {
            float4 qa = *(const float4*)(ldsQ + np * 68 + dd);
            float4 qb = *(const float4*)(ldsQ + (np + 1) * 68 + dd);
            float4 ka = *(const float4*)(ldsK + mp * 68 + dd);
            float4 kb = *(const float4*)(ldsK + (mp + 1) * 68 + dd);
            a00 += qa.x * ka.x + qa.y * ka.y + qa.z * ka.z + qa.w * ka.w;
            a01 += qa.x * kb.x + qa.y * kb.y + qa.z * kb.z + qa.w * kb.w;
            a10 += qb.x * ka.x + qb.y * ka.y + qb.z * ka.z + qb.w * ka.w;
            a11 += qb.x * kb.x + qb.y * kb.y + qb.z * kb.z + qb.w * kb.w;
        }
    }
    int n = nt * 32 + np, m = mt * 32 + mp;
    size_t sb = (size_t)split * (16 * NQ * NQ) + ((size_t)bh * NQ + n) * NQ + m;
    Spart[sb]          = a00;
    Spart[sb + 1]      = a01;
    Spart[sb + NQ]     = a10;
    Spart[sb + NQ + 1] = a11;
}

// ---------------- Kernel 4: sum partials, scale, softmax over m, write P^T -------
__global__ __launch_bounds__(256) void k_softmax(const float* __restrict__ Spart,
                                                 const float* __restrict__ nbuf,
                                                 const float* __restrict__ temp,
                                                 float* __restrict__ PT) {
    const int SS = 16 * NQ * NQ;
    int r    = blockIdx.x * 4 + (threadIdx.x >> 6);   // row id 0..2559 (= bh*160+n)
    int lane = threadIdx.x & 63;
    const float* Sr = Spart + (size_t)r * NQ;
    float v0 = 0.f, v1 = 0.f, v2 = 0.f;
#pragma unroll
    for (int sp = 0; sp < 4; ++sp) {
        v0 += Sr[sp * SS + lane];
        v1 += Sr[sp * SS + lane + 64];
        if (lane < 32) v2 += Sr[sp * SS + lane + 128];
    }
    int bh = r / NQ, n = r - bh * NQ;
    int b  = bh >> 2, h = bh & 3;
    const float eps = 1e-12f;
    float tp  = temp[h];
    float iqn = tp / fmaxf(sqrtf(nbuf[b * 1280 + h * 160 + n]), eps);       // uniform
    float ik0 = 1.f / fmaxf(sqrtf(nbuf[b * 1280 + 640 + h * 160 + lane]), eps);
    float ik1 = 1.f / fmaxf(sqrtf(nbuf[b * 1280 + 640 + h * 160 + lane + 64]), eps);
    float ik2 = (lane < 32) ? 1.f / fmaxf(sqrtf(nbuf[b * 1280 + 640 + h * 160 + lane + 128]), eps) : 1.f;
    v0 *= iqn * ik0;
    v1 *= iqn * ik1;
    v2 = (lane < 32) ? v2 * iqn * ik2 : -1e30f;
    float mx = fmaxf(fmaxf(v0, v1), v2);
#pragma unroll
    for (int off = 32; off > 0; off >>= 1) mx = fmaxf(mx, __shfl_xor(mx, off));
    float e0 = expf(v0 - mx), e1 = expf(v1 - mx);
    float e2 = (lane < 32) ? expf(v2 - mx) : 0.f;
    float sm = e0 + e1 + e2;
#pragma unroll
    for (int off = 32; off > 0; off >>= 1) sm += __shfl_xor(sm, off);
    float inv = 1.f / sm;
    float* Pb = PT + (size_t)bh * NQ * NQ + n;
    Pb[(size_t)lane * NQ]        = e0 * inv;
    Pb[(size_t)(lane + 64) * NQ] = e1 * inv;
    if (lane < 32) Pb[(size_t)(lane + 128) * NQ] = e2 * inv;
}

// ---------------- Kernel 5: O = P V ----------------------------------------------
__global__ __launch_bounds__(256) void k_pv(const float* __restrict__ Bq,
                                            const float* __restrict__ PT,
                                            float* __restrict__ O) {
    int blk  = blockIdx.x;
    int nq   = blk & 7;
    int dt   = (blk >> 3) & 7;
    int bh   = blk >> 6;
    int b    = bh >> 2, h = bh & 3;
    int d    = dt * 512 + threadIdx.x * 2;
    int n0   = nq * 20;
    const float* Vb  = Bq + ((size_t)(b * C3 + 128 + h * CPH) * TT) * HW;
    const float* PTb = PT + (size_t)bh * NQ * NQ;
    float* Ob = O + ((size_t)(b * DIM + h * CPH) * TT) * HW;
    float2 acc[20];
#pragma unroll
    for (int j = 0; j < 20; ++j) acc[j] = make_float2(0.f, 0.f);
    for (int m = 0; m < NQ; ++m) {
        float2 vv = *(const float2*)(Vb + (size_t)m * HW + d);
        const float* pr = PTb + m * NQ + n0;      // uniform -> s_load
#pragma unroll
        for (int j = 0; j < 20; ++j) {
            acc[j].x += pr[j] * vv.x;
            acc[j].y += pr[j] * vv.y;
        }
    }
#pragma unroll
    for (int j = 0; j < 20; ++j)
        *(float2*)(Ob + (size_t)(n0 + j) * HW + d) = acc[j];
}

extern "C" void kernel_launch(void* const* d_in, const int* in_sizes, int n_in,
                              void* d_out, int out_size, void* d_ws, size_t ws_size,
                              hipStream_t stream) {
    const float* x    = (const float*)d_in[0];
    const float* wqkv = (const float*)d_in[1];
    const float* wdw  = (const float*)d_in[2];
    const float* wt   = (const float*)d_in[3];
    const float* bt   = (const float*)d_in[4];
    const float* temp = (const float*)d_in[5];
    const float* wout = (const float*)d_in[6];
    float* out = (float*)d_out;

    const size_t SA = (size_t)BB * C3 * TT * HW;       // 31,457,280 floats
    const size_t SN = (size_t)BB * 128 * TT;           // 5,120
    const size_t SS = (size_t)16 * NQ * NQ;            // 409,600
    const size_t SO = (size_t)BB * DIM * TT * HW;      // 10,485,760

    float* bufA = (float*)d_ws;          // region0: qkv-proj out; later reused
    float* bufB = bufA + SA;             // conv+temporal out (q|k|v)
    float* nbuf = bufB + SA;             // q/k row sumsq
    float* wT1  = nbuf + SN;             // transposed w_qkv [64][192]
    float* wT2  = wT1 + 64 * C3;         // transposed w_out [64][64]
    // reuse region0 after k_conv_temporal consumed bufA:
    float* Obuf  = bufA;                 // attn output (SO floats)
    float* Spart = bufA + SO;            // partial scores (4*SS floats)
    float* PTbf  = Spart + 4 * SS;       // P^T (SS floats)

    if (ws_size < (2 * SA + SN + 64 * C3 + 64 * DIM) * sizeof(float)) return;

    (void)hipMemsetAsync(nbuf, 0, SN * sizeof(float), stream);

    k_transpose<<<dim3(48), dim3(256), 0, stream>>>(wqkv, wT1, C3, DIM);
    k_transpose<<<dim3(16), dim3(256), 0, stream>>>(wout, wT2, DIM, DIM);

    k_proj<16><<<dim3(160, 12), dim3(256), 0, stream>>>(x, wT1, bufA, C3);
    k_conv_temporal<<<dim3(3072), dim3(256), 0, stream>>>(bufA, wdw, wt, bt, bufB, nbuf);
    k_scores<<<dim3(400, 4), dim3(256), 0, stream>>>(bufB, Spart);
    k_softmax<<<dim3(640), dim3(256), 0, stream>>>(Spart, nbuf, temp, PTbf);
    k_pv<<<dim3(1024), dim3(256), 0, stream>>>(bufB, PTbf, Obuf);
    k_proj<8><<<dim3(160, 8), dim3(256), 0, stream>>>(Obuf, wT2, out, DIM);
}

// Round 8
// 415.963 us; speedup vs baseline: 1.6465x; 1.0149x over previous
//
#include <hip/hip_runtime.h>

// AttentionCTS: qkv proj -> depthwise 3x3 conv -> temporal mix -> L2-norm
// q,k -> softmax(q k^T * temp) v -> out proj.   All f32 (no fp32 MFMA on CDNA4).

#define BB   4
#define DIM  64
#define HEADS 4
#define TT   10
#define HH   64
#define WW2  64
#define HW   4096          // HH*WW2
#define CPH  16            // DIM/HEADS
#define NQ   160           // CPH*TT
#define C3   192           // 3*DIM
#define NSPLIT 8           // d-splits for scores

// ---------------- Kernel 0: weight transpose (tiny) ------------------------------
__global__ __launch_bounds__(256) void k_transpose(const float* __restrict__ w,
                                                   float* __restrict__ wT,
                                                   int O, int C) {
    int idx = blockIdx.x * 256 + threadIdx.x;
    if (idx < O * C) {
        int o = idx / C, c = idx - o * C;
        wT[c * O + o] = w[idx];
    }
}

// ---------------- Kernel 1/6: pointwise projection (register-blocked GEMM) -------
template<int CHUNK>
__global__ __launch_bounds__(256) void k_proj(const float* __restrict__ x,
                                              const float* __restrict__ wT,  // [DIM][cout_total]
                                              float* __restrict__ out,
                                              int cout_total) {
    int P   = blockIdx.x * 1024 + threadIdx.x * 4;   // position over (b,t,hw)
    int b   = P / (TT * HW);
    int rem = P - b * (TT * HW);
    int t   = rem >> 12;
    int hw  = rem & 4095;
    int o0  = blockIdx.y * CHUNK;
    const float* xp = x + ((size_t)(b * DIM) * TT + t) * HW + hw;
    float4 acc[CHUNK];
#pragma unroll
    for (int o = 0; o < CHUNK; ++o) acc[o] = make_float4(0.f, 0.f, 0.f, 0.f);
    for (int c = 0; c < DIM; ++c) {
        float4 xv = *(const float4*)(xp + (size_t)c * TT * HW);
        const float* wr = wT + c * cout_total + o0;      // uniform -> s_load x4
#pragma unroll
        for (int o = 0; o < CHUNK; ++o) {
            float wv = wr[o];
            acc[o].x += wv * xv.x;
            acc[o].y += wv * xv.y;
            acc[o].z += wv * xv.z;
            acc[o].w += wv * xv.w;
        }
    }
    float* op = out + ((size_t)b * cout_total * TT + t) * HW + hw;
#pragma unroll
    for (int o = 0; o < CHUNK; ++o)
        *(float4*)(op + (size_t)(o0 + o) * TT * HW) = acc[o];
}

// ---------------- Kernel 2: depthwise 3x3 conv + temporal mix + q/k sumsq -------
__global__ __launch_bounds__(256) void k_conv_temporal(const float* __restrict__ A,
                                                       const float* __restrict__ wdw,
                                                       const float* __restrict__ wt,
                                                       const float* __restrict__ bt,
                                                       float* __restrict__ Bq,
                                                       float* __restrict__ nbuf) {
    int tid  = threadIdx.x;
    int lane = tid & 63;
    int wv   = tid >> 6;
    int li   = lane & 15;                  // w-group: w = li*4
    int g    = lane >> 4;                  // row within wave's 4-row strip
    int blk  = blockIdx.x;                 // (b*C3 + c)*4 + quarter
    int qt   = blk & 3;
    int c    = (blk >> 2) % C3;
    int b    = blk / (4 * C3);
    int row  = qt * 16 + wv * 4 + g;

    float wd[9];
#pragma unroll
    for (int k = 0; k < 9; ++k) wd[k] = wdw[c * 9 + k];    // uniform -> sgpr

    const float* Ab = A + (size_t)(b * C3 + c) * TT * HW + row * WW2 + li * 4;
    bool hasU = (row > 0), hasD = (row < HH - 1);
    const float4 z4 = make_float4(0.f, 0.f, 0.f, 0.f);

    float4 cv4[TT];
#pragma unroll
    for (int t = 0; t < TT; ++t) {
        const float* p = Ab + (size_t)t * HW;
        float4 u = hasU ? *(const float4*)(p - WW2) : z4;
        float4 m = *(const float4*)(p);
        float4 d = hasD ? *(const float4*)(p + WW2) : z4;
        float uL = __shfl_up(u.w, 1);   if (li == 0)  uL = 0.f;
        float mL = __shfl_up(m.w, 1);   if (li == 0)  mL = 0.f;
        float dL = __shfl_up(d.w, 1);   if (li == 0)  dL = 0.f;
        float uR = __shfl_down(u.x, 1); if (li == 15) uR = 0.f;
        float mR = __shfl_down(m.x, 1); if (li == 15) mR = 0.f;
        float dR = __shfl_down(d.x, 1); if (li == 15) dR = 0.f;
        float4 r;
        r.x = uL  * wd[0] + u.x * wd[1] + u.y * wd[2]
            + mL  * wd[3] + m.x * wd[4] + m.y * wd[5]
            + dL  * wd[6] + d.x * wd[7] + d.y * wd[8];
        r.y = u.x * wd[0] + u.y * wd[1] + u.z * wd[2]
            + m.x * wd[3] + m.y * wd[4] + m.z * wd[5]
            + d.x * wd[6] + d.y * wd[7] + d.z * wd[8];
        r.z = u.y * wd[0] + u.z * wd[1] + u.w * wd[2]
            + m.y * wd[3] + m.z * wd[4] + m.w * wd[5]
            + d.y * wd[6] + d.z * wd[7] + d.w * wd[8];
        r.w = u.z * wd[0] + u.w * wd[1] + uR  * wd[2]
            + m.z * wd[3] + m.w * wd[4] + mR  * wd[5]
            + d.z * wd[6] + d.w * wd[7] + dR  * wd[8];
        cv4[t] = r;
    }

    size_t obase = (size_t)(b * C3 + c) * TT * HW + row * WW2 + li * 4;
    bool doSS = (c < 128);
    float ss[TT];
#pragma unroll
    for (int s = 0; s < TT; ++s) {
        float bs = bt[s];
        float4 ov = make_float4(bs, bs, bs, bs);
#pragma unroll
        for (int t = 0; t < TT; ++t) {
            float wv_ = wt[s * TT + t];
            ov.x += cv4[t].x * wv_;
            ov.y += cv4[t].y * wv_;
            ov.z += cv4[t].z * wv_;
            ov.w += cv4[t].w * wv_;
        }
        *(float4*)(Bq + obase + (size_t)s * HW) = ov;
        ss[s] = ov.x * ov.x + ov.y * ov.y + ov.z * ov.z + ov.w * ov.w;
    }

    if (doSS) {
#pragma unroll
        for (int off = 32; off > 0; off >>= 1) {
#pragma unroll
            for (int s = 0; s < TT; ++s) ss[s] += __shfl_xor(ss[s], off);
        }
        if (lane == 0) {
#pragma unroll
            for (int s = 0; s < TT; ++s)
                atomicAdd(&nbuf[(size_t)(b * 128 + c) * TT + s], ss[s]);
        }
    }
}

// ---------------- Kernel 3: partial scores S_part[split] = q k^T over d-chunk ----
// 1-D grid 3200 blocks, XCD-swizzled so all 25 tile-blocks of one (bh,split)
// group land on one XCD (Q/K re-reads hit that XCD's L2).
// Micro-tile rows {r, r+16}: ldsK lane-reads stride 1 row -> 2-way alias (free).
__global__ __launch_bounds__(256) void k_scores(const float* __restrict__ Bq,
                                                float* __restrict__ Spart) {
    __shared__ float ldsQ[32 * 68];
    __shared__ float ldsK[32 * 68];
    int gblk    = blockIdx.x;                 // 0..3199
    int logical = (gblk & 7) * 400 + (gblk >> 3);
    int split   = logical / 400;              // 0..7 (each XCD owns one split)
    int rem     = logical - split * 400;
    int bh      = rem / 25;
    int rr      = rem - bh * 25;
    int nt = rr / 5, mt = rr - nt * 5;
    int b = bh >> 2, h = bh & 3;
    const float* Qb = Bq + ((size_t)(b * C3 + h * CPH) * TT) * HW + (size_t)nt * 32 * HW;
    const float* Kb = Bq + ((size_t)(b * C3 + 64 + h * CPH) * TT) * HW + (size_t)mt * 32 * HW;
    int tid = threadIdx.x;
    int r   = tid >> 3, cg = (tid & 7) * 8;
    int qr  = tid >> 4;            // 0..15
    int kr  = tid & 15;            // 0..15
    float a00 = 0, a01 = 0, a10 = 0, a11 = 0;
    int dlo = split * (HW / NSPLIT), dhi = dlo + (HW / NSPLIT);
    for (int d0 = dlo; d0 < dhi; d0 += 64) {
        __syncthreads();
        float4 q0 = *(const float4*)(Qb + (size_t)r * HW + d0 + cg);
        float4 q1 = *(const float4*)(Qb + (size_t)r * HW + d0 + cg + 4);
        float4 k0 = *(const float4*)(Kb + (size_t)r * HW + d0 + cg);
        float4 k1 = *(const float4*)(Kb + (size_t)r * HW + d0 + cg + 4);
        *(float4*)(ldsQ + r * 68 + cg)     = q0;
        *(float4*)(ldsQ + r * 68 + cg + 4) = q1;
        *(float4*)(ldsK + r * 68 + cg)     = k0;
        *(float4*)(ldsK + r * 68 + cg + 4) = k1;
        __syncthreads();
#pragma unroll
        for (int dd = 0; dd < 64; dd += 4) {
            float4 qa = *(const float4*)(ldsQ + qr * 68 + dd);
            float4 qb = *(const float4*)(ldsQ + (qr + 16) * 68 + dd);
            float4 ka = *(const float4*)(ldsK + kr * 68 + dd);
            float4 kb = *(const float4*)(ldsK + (kr + 16) * 68 + dd);
            a00 += qa.x * ka.x + qa.y * ka.y + qa.z * ka.z + qa.w * ka.w;
            a01 += qa.x * kb.x + qa.y * kb.y + qa.z * kb.z + qa.w * kb.w;
            a10 += qb.x * ka.x + qb.y * ka.y + qb.z * ka.z + qb.w * ka.w;
            a11 += qb.x * kb.x + qb.y * kb.y + qb.z * kb.z + qb.w * kb.w;
        }
    }
    int n = nt * 32, m = mt * 32;
    size_t sb = (size_t)split * (16 * NQ * NQ)
              + ((size_t)bh * NQ + n + qr) * NQ + m + kr;
    Spart[sb]               = a00;
    Spart[sb + 16]          = a01;
    Spart[sb + 16 * NQ]     = a10;
    Spart[sb + 16 * NQ + 16] = a11;
}

// ---------------- Kernel 4: sum partials, scale, softmax over m, write P^T -------
__global__ __launch_bounds__(256) void k_softmax(const float* __restrict__ Spart,
                                                 const float* __restrict__ nbuf,
                                                 const float* __restrict__ temp,
                                                 float* __restrict__ PT) {
    const int SS = 16 * NQ * NQ;
    int r    = blockIdx.x * 4 + (threadIdx.x >> 6);   // row id 0..2559 (= bh*160+n)
    int lane = threadIdx.x & 63;
    const float* Sr = Spart + (size_t)r * NQ;
    float v0 = 0.f, v1 = 0.f, v2 = 0.f;
#pragma unroll
    for (int sp = 0; sp < NSPLIT; ++sp) {
        v0 += Sr[sp * SS + lane];
        v1 += Sr[sp * SS + lane + 64];
        if (lane < 32) v2 += Sr[sp * SS + lane + 128];
    }
    int bh = r / NQ, n = r - bh * NQ;
    int b  = bh >> 2, h = bh & 3;
    const float eps = 1e-12f;
    float tp  = temp[h];
    float iqn = tp / fmaxf(sqrtf(nbuf[b * 1280 + h * 160 + n]), eps);       // uniform
    float ik0 = 1.f / fmaxf(sqrtf(nbuf[b * 1280 + 640 + h * 160 + lane]), eps);
    float ik1 = 1.f / fmaxf(sqrtf(nbuf[b * 1280 + 640 + h * 160 + lane + 64]), eps);
    float ik2 = (lane < 32) ? 1.f / fmaxf(sqrtf(nbuf[b * 1280 + 640 + h * 160 + lane + 128]), eps) : 1.f;
    v0 *= iqn * ik0;
    v1 *= iqn * ik1;
    v2 = (lane < 32) ? v2 * iqn * ik2 : -1e30f;
    float mx = fmaxf(fmaxf(v0, v1), v2);
#pragma unroll
    for (int off = 32; off > 0; off >>= 1) mx = fmaxf(mx, __shfl_xor(mx, off));
    float e0 = expf(v0 - mx), e1 = expf(v1 - mx);
    float e2 = (lane < 32) ? expf(v2 - mx) : 0.f;
    float sm = e0 + e1 + e2;
#pragma unroll
    for (int off = 32; off > 0; off >>= 1) sm += __shfl_xor(sm, off);
    float inv = 1.f / sm;
    float* Pb = PT + (size_t)bh * NQ * NQ + n;
    Pb[(size_t)lane * NQ]        = e0 * inv;
    Pb[(size_t)(lane + 64) * NQ] = e1 * inv;
    if (lane < 32) Pb[(size_t)(lane + 128) * NQ] = e2 * inv;
}

// ---------------- Kernel 5: O = P V ----------------------------------------------
// 1-D grid 1024, XCD-swizzled so the 8 nq-blocks sharing one (bh,dt) V panel
// land on one XCD.
__global__ __launch_bounds__(256) void k_pv(const float* __restrict__ Bq,
                                            const float* __restrict__ PT,
                                            float* __restrict__ O) {
    int gblk    = blockIdx.x;                 // 0..1023
    int logical = (gblk & 7) * 128 + (gblk >> 3);
    int nq   = logical & 7;
    int dt   = (logical >> 3) & 7;
    int bh   = logical >> 6;
    int b    = bh >> 2, h = bh & 3;
    int d    = dt * 512 + threadIdx.x * 2;
    int n0   = nq * 20;
    const float* Vb  = Bq + ((size_t)(b * C3 + 128 + h * CPH) * TT) * HW;
    const float* PTb = PT + (size_t)bh * NQ * NQ;
    float* Ob = O + ((size_t)(b * DIM + h * CPH) * TT) * HW;
    float2 acc[20];
#pragma unroll
    for (int j = 0; j < 20; ++j) acc[j] = make_float2(0.f, 0.f);
    for (int m = 0; m < NQ; ++m) {
        float2 vv = *(const float2*)(Vb + (size_t)m * HW + d);
        const float* pr = PTb + m * NQ + n0;      // uniform -> s_load
#pragma unroll
        for (int j = 0; j < 20; ++j) {
            acc[j].x += pr[j] * vv.x;
            acc[j].y += pr[j] * vv.y;
        }
    }
#pragma unroll
    for (int j = 0; j < 20; ++j)
        *(float2*)(Ob + (size_t)(n0 + j) * HW + d) = acc[j];
}

extern "C" void kernel_launch(void* const* d_in, const int* in_sizes, int n_in,
                              void* d_out, int out_size, void* d_ws, size_t ws_size,
                              hipStream_t stream) {
    const float* x    = (const float*)d_in[0];
    const float* wqkv = (const float*)d_in[1];
    const float* wdw  = (const float*)d_in[2];
    const float* wt   = (const float*)d_in[3];
    const float* bt   = (const float*)d_in[4];
    const float* temp = (const float*)d_in[5];
    const float* wout = (const float*)d_in[6];
    float* out = (float*)d_out;

    const size_t SA = (size_t)BB * C3 * TT * HW;       // 31,457,280 floats
    const size_t SN = (size_t)BB * 128 * TT;           // 5,120
    const size_t SS = (size_t)16 * NQ * NQ;            // 409,600
    const size_t SO = (size_t)BB * DIM * TT * HW;      // 10,485,760

    float* bufA = (float*)d_ws;          // region0: qkv-proj out; later reused
    float* bufB = bufA + SA;             // conv+temporal out (q|k|v)
    float* nbuf = bufB + SA;             // q/k row sumsq
    float* wT1  = nbuf + SN;             // transposed w_qkv [64][192]
    float* wT2  = wT1 + 64 * C3;         // transposed w_out [64][64]
    // reuse region0 after k_conv_temporal consumed bufA:
    float* Obuf  = bufA;                 // attn output (SO floats)
    float* Spart = bufA + SO;            // partial scores (NSPLIT*SS floats)
    float* PTbf  = Spart + NSPLIT * SS;  // P^T (SS floats)

    if (ws_size < (2 * SA + SN + 64 * C3 + 64 * DIM) * sizeof(float)) return;

    (void)hipMemsetAsync(nbuf, 0, SN * sizeof(float), stream);

    k_transpose<<<dim3(48), dim3(256), 0, stream>>>(wqkv, wT1, C3, DIM);
    k_transpose<<<dim3(16), dim3(256), 0, stream>>>(wout, wT2, DIM, DIM);

    k_proj<16><<<dim3(160, 12), dim3(256), 0, stream>>>(x, wT1, bufA, C3);
    k_conv_temporal<<<dim3(3072), dim3(256), 0, stream>>>(bufA, wdw, wt, bt, bufB, nbuf);
    k_scores<<<dim3(16 * 25 * NSPLIT), dim3(256), 0, stream>>>(bufB, Spart);
    k_softmax<<<dim3(640), dim3(256), 0, stream>>>(Spart, nbuf, temp, PTbf);
    k_pv<<<dim3(1024), dim3(256), 0, stream>>>(bufB, PTbf, Obuf);
    k_proj<8><<<dim3(160, 8), dim3(256), 0, stream>>>(Obuf, wT2, out, DIM);
}

// Round 9
// 379.776 us; speedup vs baseline: 1.8034x; 1.0953x over previous
//
#include <hip/hip_runtime.h>

// AttentionCTS: qkv proj -> depthwise 3x3 conv -> temporal mix -> L2-norm
// q,k -> softmax(q k^T * temp) v -> out proj.   All f32 (no fp32 MFMA on CDNA4).

#define BB   4
#define DIM  64
#define HEADS 4
#define TT   10
#define HH   64
#define WW2  64
#define HW   4096          // HH*WW2
#define CPH  16            // DIM/HEADS
#define NQ   160           // CPH*TT
#define C3   192           // 3*DIM
#define NSPLIT 8           // d-splits for scores

// ---------------- Kernel 0: weight transpose (tiny) ------------------------------
__global__ __launch_bounds__(256) void k_transpose(const float* __restrict__ w,
                                                   float* __restrict__ wT,
                                                   int O, int C) {
    int idx = blockIdx.x * 256 + threadIdx.x;
    if (idx < O * C) {
        int o = idx / C, c = idx - o * C;
        wT[c * O + o] = w[idx];
    }
}

// ---------------- Kernel 1/6: pointwise projection (register-blocked GEMM) -------
template<int CHUNK>
__global__ __launch_bounds__(256) void k_proj(const float* __restrict__ x,
                                              const float* __restrict__ wT,  // [DIM][cout_total]
                                              float* __restrict__ out,
                                              int cout_total) {
    int P   = blockIdx.x * 1024 + threadIdx.x * 4;   // position over (b,t,hw)
    int b   = P / (TT * HW);
    int rem = P - b * (TT * HW);
    int t   = rem >> 12;
    int hw  = rem & 4095;
    int o0  = blockIdx.y * CHUNK;
    const float* xp = x + ((size_t)(b * DIM) * TT + t) * HW + hw;
    float4 acc[CHUNK];
#pragma unroll
    for (int o = 0; o < CHUNK; ++o) acc[o] = make_float4(0.f, 0.f, 0.f, 0.f);
    for (int c = 0; c < DIM; ++c) {
        float4 xv = *(const float4*)(xp + (size_t)c * TT * HW);
        const float* wr = wT + c * cout_total + o0;      // uniform -> s_load x4
#pragma unroll
        for (int o = 0; o < CHUNK; ++o) {
            float wv = wr[o];
            acc[o].x += wv * xv.x;
            acc[o].y += wv * xv.y;
            acc[o].z += wv * xv.z;
            acc[o].w += wv * xv.w;
        }
    }
    float* op = out + ((size_t)b * cout_total * TT + t) * HW + hw;
#pragma unroll
    for (int o = 0; o < CHUNK; ++o)
        *(float4*)(op + (size_t)(o0 + o) * TT * HW) = acc[o];
}

// ---------------- Kernel 2: depthwise 3x3 conv + fused temporal mix + q/k sumsq --
// float4-per-lane, 4-row strip per wave.  Temporal mix merged into the t-loop
// (ov4[s] += conv_t * wt[s][t]) so each load batch is followed by ~76 FMAs;
// 1-deep software prefetch of the next t's 3 rows keeps a batch in flight.
__global__ __launch_bounds__(256) void k_conv_temporal(const float* __restrict__ A,
                                                       const float* __restrict__ wdw,
                                                       const float* __restrict__ wt,
                                                       const float* __restrict__ bt,
                                                       float* __restrict__ Bq,
                                                       float* __restrict__ nbuf) {
    int tid  = threadIdx.x;
    int lane = tid & 63;
    int wv   = tid >> 6;
    int li   = lane & 15;                  // w-group: w = li*4
    int g    = lane >> 4;                  // row within wave's 4-row strip
    int blk  = blockIdx.x;                 // (b*C3 + c)*4 + quarter
    int qt   = blk & 3;
    int c    = (blk >> 2) % C3;
    int b    = blk / (4 * C3);
    int row  = qt * 16 + wv * 4 + g;

    float wd[9];
#pragma unroll
    for (int k = 0; k < 9; ++k) wd[k] = wdw[c * 9 + k];    // uniform -> sgpr

    const float* Ab = A + (size_t)(b * C3 + c) * TT * HW + row * WW2 + li * 4;
    bool hasU = (row > 0), hasD = (row < HH - 1);
    const float4 z4 = make_float4(0.f, 0.f, 0.f, 0.f);

    float4 ov4[TT];
#pragma unroll
    for (int s = 0; s < TT; ++s) {
        float bs = bt[s];
        ov4[s] = make_float4(bs, bs, bs, bs);
    }

    // prefetch t=0
    float4 u = hasU ? *(const float4*)(Ab - WW2) : z4;
    float4 m = *(const float4*)(Ab);
    float4 d = hasD ? *(const float4*)(Ab + WW2) : z4;

#pragma unroll
    for (int t = 0; t < TT; ++t) {
        float4 un, mn, dn;
        if (t < TT - 1) {                   // issue next batch before computing
            const float* p = Ab + (size_t)(t + 1) * HW;
            un = hasU ? *(const float4*)(p - WW2) : z4;
            mn = *(const float4*)(p);
            dn = hasD ? *(const float4*)(p + WW2) : z4;
        }
        float uL = __shfl_up(u.w, 1);   if (li == 0)  uL = 0.f;
        float mL = __shfl_up(m.w, 1);   if (li == 0)  mL = 0.f;
        float dL = __shfl_up(d.w, 1);   if (li == 0)  dL = 0.f;
        float uR = __shfl_down(u.x, 1); if (li == 15) uR = 0.f;
        float mR = __shfl_down(m.x, 1); if (li == 15) mR = 0.f;
        float dR = __shfl_down(d.x, 1); if (li == 15) dR = 0.f;
        float4 r;
        r.x = uL  * wd[0] + u.x * wd[1] + u.y * wd[2]
            + mL  * wd[3] + m.x * wd[4] + m.y * wd[5]
            + dL  * wd[6] + d.x * wd[7] + d.y * wd[8];
        r.y = u.x * wd[0] + u.y * wd[1] + u.z * wd[2]
            + m.x * wd[3] + m.y * wd[4] + m.z * wd[5]
            + d.x * wd[6] + d.y * wd[7] + d.z * wd[8];
        r.z = u.y * wd[0] + u.z * wd[1] + u.w * wd[2]
            + m.y * wd[3] + m.z * wd[4] + m.w * wd[5]
            + d.y * wd[6] + d.z * wd[7] + d.w * wd[8];
        r.w = u.z * wd[0] + u.w * wd[1] + uR  * wd[2]
            + m.z * wd[3] + m.w * wd[4] + mR  * wd[5]
            + d.z * wd[6] + d.w * wd[7] + dR  * wd[8];
#pragma unroll
        for (int s = 0; s < TT; ++s) {      // fused temporal accumulation
            float wv_ = wt[s * TT + t];     // uniform -> s_load
            ov4[s].x += r.x * wv_;
            ov4[s].y += r.y * wv_;
            ov4[s].z += r.z * wv_;
            ov4[s].w += r.w * wv_;
        }
        u = un; m = mn; d = dn;
    }

    size_t obase = (size_t)(b * C3 + c) * TT * HW + row * WW2 + li * 4;
    float ss[TT];
#pragma unroll
    for (int s = 0; s < TT; ++s) {
        *(float4*)(Bq + obase + (size_t)s * HW) = ov4[s];
        ss[s] = ov4[s].x * ov4[s].x + ov4[s].y * ov4[s].y
              + ov4[s].z * ov4[s].z + ov4[s].w * ov4[s].w;
    }

    if (c < 128) {                          // q or k row: accumulate sumsq
#pragma unroll
        for (int off = 32; off > 0; off >>= 1) {
#pragma unroll
            for (int s = 0; s < TT; ++s) ss[s] += __shfl_xor(ss[s], off);
        }
        if (lane == 0) {
#pragma unroll
            for (int s = 0; s < TT; ++s)
                atomicAdd(&nbuf[(size_t)(b * 128 + c) * TT + s], ss[s]);
        }
    }
}

// ---------------- Kernel 3: partial scores S_part[split] = q k^T over d-chunk ----
__global__ __launch_bounds__(256) void k_scores(const float* __restrict__ Bq,
                                                float* __restrict__ Spart) {
    __shared__ float ldsQ[32 * 68];
    __shared__ float ldsK[32 * 68];
    int gblk    = blockIdx.x;                 // 0..3199
    int logical = (gblk & 7) * 400 + (gblk >> 3);
    int split   = logical / 400;              // 0..7 (each XCD owns one split)
    int rem     = logical - split * 400;
    int bh      = rem / 25;
    int rr      = rem - bh * 25;
    int nt = rr / 5, mt = rr - nt * 5;
    int b = bh >> 2, h = bh & 3;
    const float* Qb = Bq + ((size_t)(b * C3 + h * CPH) * TT) * HW + (size_t)nt * 32 * HW;
    const float* Kb = Bq + ((size_t)(b * C3 + 64 + h * CPH) * TT) * HW + (size_t)mt * 32 * HW;
    int tid = threadIdx.x;
    int r   = tid >> 3, cg = (tid & 7) * 8;
    int qr  = tid >> 4;            // 0..15
    int kr  = tid & 15;            // 0..15
    float a00 = 0, a01 = 0, a10 = 0, a11 = 0;
    int dlo = split * (HW / NSPLIT), dhi = dlo + (HW / NSPLIT);
    for (int d0 = dlo; d0 < dhi; d0 += 64) {
        __syncthreads();
        float4 q0 = *(const float4*)(Qb + (size_t)r * HW + d0 + cg);
        float4 q1 = *(const float4*)(Qb + (size_t)r * HW + d0 + cg + 4);
        float4 k0 = *(const float4*)(Kb + (size_t)r * HW + d0 + cg);
        float4 k1 = *(const float4*)(Kb + (size_t)r * HW + d0 + cg + 4);
        *(float4*)(ldsQ + r * 68 + cg)     = q0;
        *(float4*)(ldsQ + r * 68 + cg + 4) = q1;
        *(float4*)(ldsK + r * 68 + cg)     = k0;
        *(float4*)(ldsK + r * 68 + cg + 4) = k1;
        __syncthreads();
#pragma unroll
        for (int dd = 0; dd < 64; dd += 4) {
            float4 qa = *(const float4*)(ldsQ + qr * 68 + dd);
            float4 qb = *(const float4*)(ldsQ + (qr + 16) * 68 + dd);
            float4 ka = *(const float4*)(ldsK + kr * 68 + dd);
            float4 kb = *(const float4*)(ldsK + (kr + 16) * 68 + dd);
            a00 += qa.x * ka.x + qa.y * ka.y + qa.z * ka.z + qa.w * ka.w;
            a01 += qa.x * kb.x + qa.y * kb.y + qa.z * kb.z + qa.w * kb.w;
            a10 += qb.x * ka.x + qb.y * ka.y + qb.z * ka.z + qb.w * ka.w;
            a11 += qb.x * kb.x + qb.y * kb.y + qb.z * kb.z + qb.w * kb.w;
        }
    }
    int n = nt * 32, m = mt * 32;
    size_t sb = (size_t)split * (16 * NQ * NQ)
              + ((size_t)bh * NQ + n + qr) * NQ + m + kr;
    Spart[sb]               = a00;
    Spart[sb + 16]          = a01;
    Spart[sb + 16 * NQ]     = a10;
    Spart[sb + 16 * NQ + 16] = a11;
}

// ---------------- Kernel 4: sum partials, scale, softmax over m, write P^T -------
__global__ __launch_bounds__(256) void k_softmax(const float* __restrict__ Spart,
                                                 const float* __restrict__ nbuf,
                                                 const float* __restrict__ temp,
                                                 float* __restrict__ PT) {
    const int SS = 16 * NQ * NQ;
    int r    = blockIdx.x * 4 + (threadIdx.x >> 6);   // row id 0..2559 (= bh*160+n)
    int lane = threadIdx.x & 63;
    const float* Sr = Spart + (size_t)r * NQ;
    float v0 = 0.f, v1 = 0.f, v2 = 0.f;
#pragma unroll
    for (int sp = 0; sp < NSPLIT; ++sp) {
        v0 += Sr[sp * SS + lane];
        v1 += Sr[sp * SS + lane + 64];
        if (lane < 32) v2 += Sr[sp * SS + lane + 128];
    }
    int bh = r / NQ, n = r - bh * NQ;
    int b  = bh >> 2, h = bh & 3;
    const float eps = 1e-12f;
    float tp  = temp[h];
    float iqn = tp / fmaxf(sqrtf(nbuf[b * 1280 + h * 160 + n]), eps);       // uniform
    float ik0 = 1.f / fmaxf(sqrtf(nbuf[b * 1280 + 640 + h * 160 + lane]), eps);
    float ik1 = 1.f / fmaxf(sqrtf(nbuf[b * 1280 + 640 + h * 160 + lane + 64]), eps);
    float ik2 = (lane < 32) ? 1.f / fmaxf(sqrtf(nbuf[b * 1280 + 640 + h * 160 + lane + 128]), eps) : 1.f;
    v0 *= iqn * ik0;
    v1 *= iqn * ik1;
    v2 = (lane < 32) ? v2 * iqn * ik2 : -1e30f;
    float mx = fmaxf(fmaxf(v0, v1), v2);
#pragma unroll
    for (int off = 32; off > 0; off >>= 1) mx = fmaxf(mx, __shfl_xor(mx, off));
    float e0 = expf(v0 - mx), e1 = expf(v1 - mx);
    float e2 = (lane < 32) ? expf(v2 - mx) : 0.f;
    float sm = e0 + e1 + e2;
#pragma unroll
    for (int off = 32; off > 0; off >>= 1) sm += __shfl_xor(sm, off);
    float inv = 1.f / sm;
    float* Pb = PT + (size_t)bh * NQ * NQ + n;
    Pb[(size_t)lane * NQ]        = e0 * inv;
    Pb[(size_t)(lane + 64) * NQ] = e1 * inv;
    if (lane < 32) Pb[(size_t)(lane + 128) * NQ] = e2 * inv;
}

// ---------------- Kernel 5: O = P V ----------------------------------------------
__global__ __launch_bounds__(256) void k_pv(const float* __restrict__ Bq,
                                            const float* __restrict__ PT,
                                            float* __restrict__ O) {
    int gblk    = blockIdx.x;                 // 0..1023
    int logical = (gblk & 7) * 128 + (gblk >> 3);
    int nq   = logical & 7;
    int dt   = (logical >> 3) & 7;
    int bh   = logical >> 6;
    int b    = bh >> 2, h = bh & 3;
    int d    = dt * 512 + threadIdx.x * 2;
    int n0   = nq * 20;
    const float* Vb  = Bq + ((size_t)(b * C3 + 128 + h * CPH) * TT) * HW;
    const float* PTb = PT + (size_t)bh * NQ * NQ;
    float* Ob = O + ((size_t)(b * DIM + h * CPH) * TT) * HW;
    float2 acc[20];
#pragma unroll
    for (int j = 0; j < 20; ++j) acc[j] = make_float2(0.f, 0.f);
    for (int m = 0; m < NQ; ++m) {
        float2 vv = *(const float2*)(Vb + (size_t)m * HW + d);
        const float* pr = PTb + m * NQ + n0;      // uniform -> s_load
#pragma unroll
        for (int j = 0; j < 20; ++j) {
            acc[j].x += pr[j] * vv.x;
            acc[j].y += pr[j] * vv.y;
        }
    }
#pragma unroll
    for (int j = 0; j < 20; ++j)
        *(float2*)(Ob + (size_t)(n0 + j) * HW + d) = acc[j];
}

extern "C" void kernel_launch(void* const* d_in, const int* in_sizes, int n_in,
                              void* d_out, int out_size, void* d_ws, size_t ws_size,
                              hipStream_t stream) {
    const float* x    = (const float*)d_in[0];
    const float* wqkv = (const float*)d_in[1];
    const float* wdw  = (const float*)d_in[2];
    const float* wt   = (const float*)d_in[3];
    const float* bt   = (const float*)d_in[4];
    const float* temp = (const float*)d_in[5];
    const float* wout = (const float*)d_in[6];
    float* out = (float*)d_out;

    const size_t SA = (size_t)BB * C3 * TT * HW;       // 31,457,280 floats
    const size_t SN = (size_t)BB * 128 * TT;           // 5,120
    const size_t SS = (size_t)16 * NQ * NQ;            // 409,600
    const size_t SO = (size_t)BB * DIM * TT * HW;      // 10,485,760

    float* bufA = (float*)d_ws;          // region0: qkv-proj out; later reused
    float* bufB = bufA + SA;             // conv+temporal out (q|k|v)
    float* nbuf = bufB + SA;             // q/k row sumsq
    float* wT1  = nbuf + SN;             // transposed w_qkv [64][192]
    float* wT2  = wT1 + 64 * C3;         // transposed w_out [64][64]
    // reuse region0 after k_conv_temporal consumed bufA:
    float* Obuf  = bufA;                 // attn output (SO floats)
    float* Spart = bufA + SO;            // partial scores (NSPLIT*SS floats)
    float* PTbf  = Spart + NSPLIT * SS;  // P^T (SS floats)

    if (ws_size < (2 * SA + SN + 64 * C3 + 64 * DIM) * sizeof(float)) return;

    (void)hipMemsetAsync(nbuf, 0, SN * sizeof(float), stream);

    k_transpose<<<dim3(48), dim3(256), 0, stream>>>(wqkv, wT1, C3, DIM);
    k_transpose<<<dim3(16), dim3(256), 0, stream>>>(wout, wT2, DIM, DIM);

    k_proj<16><<<dim3(160, 12), dim3(256), 0, stream>>>(x, wT1, bufA, C3);
    k_conv_temporal<<<dim3(3072), dim3(256), 0, stream>>>(bufA, wdw, wt, bt, bufB, nbuf);
    k_scores<<<dim3(16 * 25 * NSPLIT), dim3(256), 0, stream>>>(bufB, Spart);
    k_softmax<<<dim3(640), dim3(256), 0, stream>>>(Spart, nbuf, temp, PTbf);
    k_pv<<<dim3(1024), dim3(256), 0, stream>>>(bufB, PTbf, Obuf);
    k_proj<8><<<dim3(160, 8), dim3(256), 0, stream>>>(Obuf, wT2, out, DIM);
}